// Round 14
// baseline (38.515 us; speedup 1.0000x reference)
//
#include <hip/hip_runtime.h>
#include <hip/hip_cooperative_groups.h>
#include <stdint.h>

namespace cg = cooperative_groups;

#define BINS    64
#define SBINS   256               // sub-bins: 4 per bin (h = 1/4 bin)
#define CSTR    66                // dwords per u8-count column (64 + 2 pad); 8B aligned
#define THREADS 128
#define CHUNKS  32                // blocks per channel-image
#define NPIX    (512*512)
#define PPB     (NPIX / CHUNKS)   // 8192 px per block -> 64 px/thread (u8 max 64 < 255)
#define ITERS   (PPB / 4 / THREADS)   // 16
#define NCH     12                // 4*3 channel-images per input
#define NIMG    (2 * NCH)         // 24

__global__ __launch_bounds__(THREADS) void hist_kernel(
    const float* __restrict__ pred, const float* __restrict__ target,
    uint32_t* __restrict__ part /* [NIMG][CHUNKS][SBINS] */)
{
    __shared__ uint32_t lh[THREADS * CSTR];   // 33792 B
    __shared__ uint32_t red[2 * THREADS];     // 1 KB
    const int tid = threadIdx.x;

    uint32_t* col = &lh[tid * CSTR];
    uint2* colv = (uint2*)col;
    #pragma unroll
    for (int i = 0; i < CSTR / 2; ++i) colv[i] = make_uint2(0u, 0u);
    __syncthreads();

    const int chunk = blockIdx.x;
    const int ch    = blockIdx.y;
    const int z     = blockIdx.z;
    const float* src = (z == 0 ? pred : target)
                     + (size_t)ch * NPIX + (size_t)chunk * PPB;
    const float4* src4 = (const float4*)src;

    float4 v = src4[tid];
    #pragma unroll
    for (int k = 0; k < ITERS; ++k) {
        float4 vn = (k + 1 < ITERS) ? src4[(size_t)(k + 1) * THREADS + tid]
                                    : make_float4(0.f, 0.f, 0.f, 0.f);
        // 4 sub-bin indices + increments
        uint32_t kq0 = (uint32_t)(int)(v.x * 256.0f);
        uint32_t kq1 = (uint32_t)(int)(v.y * 256.0f);
        uint32_t kq2 = (uint32_t)(int)(v.z * 256.0f);
        uint32_t kq3 = (uint32_t)(int)(v.w * 256.0f);
        uint32_t d0 = kq0 >> 2, d1 = kq1 >> 2, d2 = kq2 >> 2, d3 = kq3 >> 2;
        uint32_t i0 = 1u << ((kq0 & 3u) << 3);
        uint32_t i1 = 1u << ((kq1 & 3u) << 3);
        uint32_t i2 = 1u << ((kq2 & 3u) << 3);
        uint32_t i3 = 1u << ((kq3 & 3u) << 3);
        // 4 independent reads (issued together: no intervening writes)
        uint32_t a0 = col[d0], a1 = col[d1], a2 = col[d2], a3 = col[d3];
        // in-register duplicate merge (exact): forward inc to last occurrence
        bool e01 = d0 == d1, e02 = d0 == d2, e03 = d0 == d3;
        bool e12 = d1 == d2, e13 = d1 == d3, e23 = d2 == d3;
        uint32_t i1f = i1 + (e01 ? i0 : 0u);
        uint32_t i2f = i2 + ((!e01 && e02) ? i0 : 0u) + (e12 ? i1f : 0u);
        uint32_t i3f = i3 + ((!e01 && !e02 && e03) ? i0 : 0u)
                          + ((!e12 && e13) ? i1f : 0u)
                          + (e23 ? i2f : 0u);
        bool s0 = e01 | e02 | e03;
        bool s1 = e12 | e13;
        bool s2 = e23;
        // suppressed writes land in pad dword 64 (never read by fold)
        col[s0 ? 64u : d0] = a0 + i0;
        col[s1 ? 64u : d1] = a1 + i1f;
        col[s2 ? 64u : d2] = a2 + i2f;
        col[d3]            = a3 + i3f;
        v = vn;
    }
    __syncthreads();

    // SIMD fold: thread t sums dword d = t&63 over 64 columns (half g = t>>6)
    // in packed u16 lanes. lo: sub-bins {4d, 4d+2}; hi: {4d+1, 4d+3}.
    const int d = tid & 63;
    const int g = tid >> 6;
    uint32_t lo = 0u, hi = 0u;
    #pragma unroll 8
    for (int c = 0; c < 64; ++c) {
        uint32_t x = lh[(g * 64 + c) * CSTR + d];
        lo += x & 0x00FF00FFu;
        hi += (x >> 8) & 0x00FF00FFu;
    }
    red[tid] = lo;
    red[THREADS + tid] = hi;
    __syncthreads();

    if (tid < 64) {
        uint32_t tlo = red[tid] + red[tid + 64];
        uint32_t thi = red[THREADS + tid] + red[THREADS + tid + 64];
        uint4 o;
        o.x = tlo & 0xFFFFu;        // sub-bin 4d
        o.y = thi & 0xFFFFu;        // sub-bin 4d+1
        o.z = tlo >> 16;            // sub-bin 4d+2
        o.w = thi >> 16;            // sub-bin 4d+3
        uint4* pp = (uint4*)(part + (((size_t)z * NCH + ch) * CHUNKS + chunk) * SBINS);
        pp[tid] = o;                // coalesced 16B/lane store
    }
}

// Cooperative: 12 blocks (one per channel pair). Fold partials for pred+target,
// 36-tap Gaussian conv, CDF, |dCDF| partial; grid sync; block 0 reduces.
__global__ __launch_bounds__(256) void pairfin_kernel(
    const uint32_t* __restrict__ part, float* __restrict__ partial,
    float* __restrict__ out)
{
    __shared__ float cntP[SBINS], cntT[SBINS];
    __shared__ float histP[BINS], histT[BINS];
    const int ci = blockIdx.x;          // channel 0..11
    const int s  = threadIdx.x;         // 0..255

    uint32_t tp = 0u, tt = 0u;
    #pragma unroll 8
    for (int i = 0; i < CHUNKS; ++i) {
        tp += part[((size_t)ci * CHUNKS + i) * SBINS + s];
        tt += part[((size_t)(NCH + ci) * CHUNKS + i) * SBINS + s];
    }
    cntP[s] = (float)tp;
    cntT[s] = (float)tt;
    __syncthreads();

    if (s < 2 * BINS) {
        const int b = s & 63;
        const float* cnt = (s < BINS) ? cntP : cntT;
        float h = 0.0f;
        #pragma unroll
        for (int u = -16; u <= 19; ++u) {
            int idx = 4 * b + u;
            if (idx >= 0 && idx < SBINS) {
                float t = (u - 1.5f) * 0.25f;
                h += __expf(-0.5f * t * t) * cnt[idx];
            }
        }
        if (s < BINS) histP[b] = h; else histT[b] = h;
    }
    __syncthreads();

    if (s < 64) {                       // wave 0: dual CDF + |diff| sum
        float cp = histP[s], ct = histT[s];
        #pragma unroll
        for (int off = 1; off < 64; off <<= 1) {
            float a = __shfl_up(cp, off, 64);
            float b = __shfl_up(ct, off, 64);
            if (s >= off) { cp += a; ct += b; }
        }
        float sp = __shfl(cp, 63, 64);
        float st = __shfl(ct, 63, 64);
        float diff = fabsf(cp / (sp + 1e-8f) - ct / (st + 1e-8f));
        #pragma unroll
        for (int off = 32; off; off >>= 1)
            diff += __shfl_xor(diff, off, 64);
        if (s == 0) partial[ci] = diff;
    }

    cg::this_grid().sync();

    if (blockIdx.x == 0 && s < 64) {
        float v = (s < NCH) ? partial[s] : 0.0f;
        #pragma unroll
        for (int off = 32; off; off >>= 1)
            v += __shfl_xor(v, off, 64);
        if (s == 0) out[0] = v / (float)(NCH * BINS);
    }
}

extern "C" void kernel_launch(void* const* d_in, const int* in_sizes, int n_in,
                              void* d_out, int out_size, void* d_ws, size_t ws_size,
                              hipStream_t stream)
{
    const float* pred   = (const float*)d_in[0];
    const float* target = (const float*)d_in[1];
    uint32_t* part    = (uint32_t*)d_ws;                    // 24*32*256 u32 = 786 KB
    float*    partial = (float*)(part + (size_t)NIMG * CHUNKS * SBINS); // 12 f32
    float*    outp    = (float*)d_out;

    hist_kernel<<<dim3(CHUNKS, NCH, 2), THREADS, 0, stream>>>(pred, target, part);

    void* args[] = { (void*)&part, (void*)&partial, (void*)&outp };
    hipLaunchCooperativeKernel((const void*)pairfin_kernel,
                               dim3(NCH), dim3(256), args, 0, stream);
}

// Round 15
// 19.459 us; speedup vs baseline: 1.9793x; 1.9793x over previous
//
#include <hip/hip_runtime.h>
#include <stdint.h>

#define BINS    64
#define SBINS   256               // sub-bins: 4 per bin (h = 1/4 bin)
#define CSTR    66                // dwords per u8-count column (64 + 2 pad); 8B aligned
#define THREADS 128
#define CHUNKS  32                // blocks per channel-image
#define NPIX    (512*512)
#define PPB     (NPIX / CHUNKS)   // 8192 px per block -> 64 px/thread (u8 max 64 < 255)
#define ITERS   (PPB / 4 / THREADS)   // 16
#define NCH     12                // 4*3 channel-images per input
#define NIMG    (2 * NCH)         // 24

__global__ __launch_bounds__(THREADS) void hist_kernel(
    const float* __restrict__ pred, const float* __restrict__ target,
    uint32_t* __restrict__ part /* [NIMG][CHUNKS][SBINS] */)
{
    __shared__ uint32_t lh[THREADS * CSTR];   // 33792 B
    __shared__ uint32_t red[2 * THREADS];     // 1 KB
    const int tid = threadIdx.x;

    uint32_t* col = &lh[tid * CSTR];
    uint2* colv = (uint2*)col;
    #pragma unroll
    for (int i = 0; i < CSTR / 2; ++i) colv[i] = make_uint2(0u, 0u);
    __syncthreads();

    const int chunk = blockIdx.x;
    const int ch    = blockIdx.y;
    const int z     = blockIdx.z;
    const float* src = (z == 0 ? pred : target)
                     + (size_t)ch * NPIX + (size_t)chunk * PPB;
    const float4* src4 = (const float4*)src;

    float4 v = src4[tid];
    #pragma unroll
    for (int k = 0; k < ITERS; ++k) {
        float4 vn = (k + 1 < ITERS) ? src4[(size_t)(k + 1) * THREADS + tid]
                                    : make_float4(0.f, 0.f, 0.f, 0.f);
        // 4 sub-bin indices + increments
        uint32_t kq0 = (uint32_t)(int)(v.x * 256.0f);
        uint32_t kq1 = (uint32_t)(int)(v.y * 256.0f);
        uint32_t kq2 = (uint32_t)(int)(v.z * 256.0f);
        uint32_t kq3 = (uint32_t)(int)(v.w * 256.0f);
        uint32_t d0 = kq0 >> 2, d1 = kq1 >> 2, d2 = kq2 >> 2, d3 = kq3 >> 2;
        uint32_t i0 = 1u << ((kq0 & 3u) << 3);
        uint32_t i1 = 1u << ((kq1 & 3u) << 3);
        uint32_t i2 = 1u << ((kq2 & 3u) << 3);
        uint32_t i3 = 1u << ((kq3 & 3u) << 3);
        // 4 independent reads (no intervening writes -> one latency window)
        uint32_t a0 = col[d0], a1 = col[d1], a2 = col[d2], a3 = col[d3];
        // in-register duplicate merge (exact): forward inc to last occurrence
        bool e01 = d0 == d1, e02 = d0 == d2, e03 = d0 == d3;
        bool e12 = d1 == d2, e13 = d1 == d3, e23 = d2 == d3;
        uint32_t i1f = i1 + (e01 ? i0 : 0u);
        uint32_t i2f = i2 + ((!e01 && e02) ? i0 : 0u) + (e12 ? i1f : 0u);
        uint32_t i3f = i3 + ((!e01 && !e02 && e03) ? i0 : 0u)
                          + ((!e12 && e13) ? i1f : 0u)
                          + (e23 ? i2f : 0u);
        bool s0 = e01 | e02 | e03;
        bool s1 = e12 | e13;
        bool s2 = e23;
        // suppressed writes land in pad dword 64 (never read by fold)
        col[s0 ? 64u : d0] = a0 + i0;
        col[s1 ? 64u : d1] = a1 + i1f;
        col[s2 ? 64u : d2] = a2 + i2f;
        col[d3]            = a3 + i3f;
        v = vn;
    }
    __syncthreads();

    // SIMD fold: thread t sums dword d = t&63 over 64 columns (half g = t>>6)
    // in packed u16 lanes. lo: sub-bins {4d, 4d+2}; hi: {4d+1, 4d+3}.
    const int d = tid & 63;
    const int g = tid >> 6;
    uint32_t lo = 0u, hi = 0u;
    #pragma unroll 8
    for (int c = 0; c < 64; ++c) {
        uint32_t x = lh[(g * 64 + c) * CSTR + d];
        lo += x & 0x00FF00FFu;
        hi += (x >> 8) & 0x00FF00FFu;
    }
    red[tid] = lo;
    red[THREADS + tid] = hi;
    __syncthreads();

    if (tid < 64) {
        uint32_t tlo = red[tid] + red[tid + 64];
        uint32_t thi = red[THREADS + tid] + red[THREADS + tid + 64];
        uint4 o;
        o.x = tlo & 0xFFFFu;        // sub-bin 4d
        o.y = thi & 0xFFFFu;        // sub-bin 4d+1
        o.z = tlo >> 16;            // sub-bin 4d+2
        o.w = thi >> 16;            // sub-bin 4d+3
        uint4* pp = (uint4*)(part + (((size_t)z * NCH + ch) * CHUNKS + chunk) * SBINS);
        pp[tid] = o;                // coalesced 16B/lane store
    }
}

// Fold chunk partials + 36-tap Gaussian conv: 24 blocks, 256 threads.
__global__ __launch_bounds__(SBINS) void reduce_conv_kernel(
    const uint32_t* __restrict__ part, float* __restrict__ chist /* [NIMG][BINS] */)
{
    __shared__ float cnt[SBINS];
    const int ci = blockIdx.x;
    const int s  = threadIdx.x;
    uint32_t tot = 0u;
    #pragma unroll 8
    for (int i = 0; i < CHUNKS; ++i)
        tot += part[((size_t)ci * CHUNKS + i) * SBINS + s];
    cnt[s] = (float)tot;
    __syncthreads();

    if (s < BINS) {
        // hist_b = sum_u K(u) * cnt[4b+u], K(u) = exp(-(((u-1.5)/4)^2)/2)
        float h = 0.0f;
        #pragma unroll
        for (int u = -16; u <= 19; ++u) {
            int idx = 4 * s + u;
            if (idx >= 0 && idx < SBINS) {
                float t = (u - 1.5f) * 0.25f;
                h += __expf(-0.5f * t * t) * cnt[idx];
            }
        }
        chist[ci * BINS + s] = h;
    }
}

__global__ __launch_bounds__(256) void finalize_kernel(
    const float* __restrict__ chist, float* __restrict__ out)
{
    __shared__ float wsum[4];
    const int tid  = threadIdx.x;
    const int lane = tid & 63;          // lane == bin
    const int w    = tid >> 6;          // wave id 0..3, handles 3 channels
    float acc = 0.0f;
    for (int c = w * 3; c < w * 3 + 3; ++c) {
        float cp = chist[c * BINS + lane];
        float ct = chist[(NCH + c) * BINS + lane];
        #pragma unroll
        for (int off = 1; off < 64; off <<= 1) {
            float a = __shfl_up(cp, off, 64);
            float b = __shfl_up(ct, off, 64);
            if (lane >= off) { cp += a; ct += b; }
        }
        float sp = __shfl(cp, 63, 64);
        float st = __shfl(ct, 63, 64);
        float diff = fabsf(cp / (sp + 1e-8f) - ct / (st + 1e-8f));
        #pragma unroll
        for (int off = 32; off; off >>= 1)
            diff += __shfl_xor(diff, off, 64);
        acc += diff;
    }
    if (lane == 0) wsum[w] = acc;
    __syncthreads();
    if (tid == 0)
        out[0] = (wsum[0] + wsum[1] + wsum[2] + wsum[3]) / (float)(NCH * BINS);
}

extern "C" void kernel_launch(void* const* d_in, const int* in_sizes, int n_in,
                              void* d_out, int out_size, void* d_ws, size_t ws_size,
                              hipStream_t stream)
{
    const float* pred   = (const float*)d_in[0];
    const float* target = (const float*)d_in[1];
    uint32_t* part  = (uint32_t*)d_ws;                    // 24*32*256 u32 = 786 KB
    float*    chist = (float*)(part + (size_t)NIMG * CHUNKS * SBINS); // 24*64 f32

    hist_kernel<<<dim3(CHUNKS, NCH, 2), THREADS, 0, stream>>>(pred, target, part);
    reduce_conv_kernel<<<NIMG, SBINS, 0, stream>>>(part, chist);
    finalize_kernel<<<1, 256, 0, stream>>>(chist, (float*)d_out);
}

// Round 16
// 17.322 us; speedup vs baseline: 2.2235x; 1.1234x over previous
//
#include <hip/hip_runtime.h>
#include <stdint.h>

#define BINS    64
#define SBINS   256               // sub-bins: 4 per bin (h = 1/4 bin)
#define CSTR    66                // dwords per u8-count column (64 + 2 pad); 8B aligned
#define THREADS 128
#define CHUNKS  32                // blocks per channel-image
#define NPIX    (512*512)
#define PPB     (NPIX / CHUNKS)   // 8192 px per block -> 64 px/thread (u8 max 64 < 255)
#define ITERS   (PPB / 4 / THREADS)   // 16
#define NCH     12                // 4*3 channel-images per input
#define NIMG    (2 * NCH)         // 24

__global__ __launch_bounds__(THREADS) void hist_kernel(
    const float* __restrict__ pred, const float* __restrict__ target,
    uint32_t* __restrict__ part /* [NIMG][CHUNKS][SBINS] */,
    uint32_t* __restrict__ ticket)
{
    __shared__ uint32_t lh[THREADS * CSTR];   // 33792 B
    __shared__ uint32_t red[2 * THREADS];     // 1 KB
    const int tid = threadIdx.x;

    if (blockIdx.x == 0 && blockIdx.y == 0 && blockIdx.z == 0 && tid == 0)
        *ticket = 0u;                         // re-arm the conv ticket each launch

    uint32_t* col = &lh[tid * CSTR];
    uint2* colv = (uint2*)col;
    #pragma unroll
    for (int i = 0; i < CSTR / 2; ++i) colv[i] = make_uint2(0u, 0u);
    __syncthreads();

    const int chunk = blockIdx.x;
    const int ch    = blockIdx.y;
    const int z     = blockIdx.z;
    const float* src = (z == 0 ? pred : target)
                     + (size_t)ch * NPIX + (size_t)chunk * PPB;
    const float4* src4 = (const float4*)src;

    // prefetch depth 2: keep ~12KB/CU of HBM reads in flight
    float4 v0 = src4[tid];
    float4 v1 = src4[THREADS + tid];
    #pragma unroll
    for (int k = 0; k < ITERS; ++k) {
        float4 v2 = (k + 2 < ITERS) ? src4[(size_t)(k + 2) * THREADS + tid]
                                    : make_float4(0.f, 0.f, 0.f, 0.f);
        float xv[4] = {v0.x, v0.y, v0.z, v0.w};
        #pragma unroll
        for (int e = 0; e < 4; ++e) {
            uint32_t kq = (uint32_t)(int)(xv[e] * 256.0f);   // sub-bin 0..255
            col[kq >> 2] += 1u << ((kq & 3u) << 3);          // u8-lane count
        }
        v0 = v1; v1 = v2;
    }
    __syncthreads();

    // SIMD fold: thread t sums dword d = t&63 over 64 columns (half g = t>>6)
    // in packed u16 lanes. lo: sub-bins {4d, 4d+2}; hi: {4d+1, 4d+3}.
    const int d = tid & 63;
    const int g = tid >> 6;
    uint32_t lo = 0u, hi = 0u;
    #pragma unroll 8
    for (int c = 0; c < 64; ++c) {
        uint32_t x = lh[(g * 64 + c) * CSTR + d];
        lo += x & 0x00FF00FFu;
        hi += (x >> 8) & 0x00FF00FFu;
    }
    red[tid] = lo;
    red[THREADS + tid] = hi;
    __syncthreads();

    if (tid < 64) {
        uint32_t tlo = red[tid] + red[tid + 64];
        uint32_t thi = red[THREADS + tid] + red[THREADS + tid + 64];
        uint4 o;
        o.x = tlo & 0xFFFFu;        // sub-bin 4d
        o.y = thi & 0xFFFFu;        // sub-bin 4d+1
        o.z = tlo >> 16;            // sub-bin 4d+2
        o.w = thi >> 16;            // sub-bin 4d+3
        uint4* pp = (uint4*)(part + (((size_t)z * NCH + ch) * CHUNKS + chunk) * SBINS);
        pp[tid] = o;                // coalesced 16B/lane store
    }
}

// 12 blocks (one per channel pair): fold partials for pred+target, 36-tap
// Gaussian conv, dual CDF, |dCDF| partial; last block (ticket) sums -> out.
__global__ __launch_bounds__(SBINS) void conv_fin_kernel(
    const uint32_t* __restrict__ part, float* __restrict__ partial,
    uint32_t* __restrict__ ticket, float* __restrict__ out)
{
    __shared__ float cntP[SBINS], cntT[SBINS];
    __shared__ float histP[BINS], histT[BINS];
    const int ci = blockIdx.x;          // channel 0..11
    const int s  = threadIdx.x;         // 0..255

    uint32_t tp = 0u, tt = 0u;
    #pragma unroll 8
    for (int i = 0; i < CHUNKS; ++i) {
        tp += part[((size_t)ci * CHUNKS + i) * SBINS + s];
        tt += part[((size_t)(NCH + ci) * CHUNKS + i) * SBINS + s];
    }
    cntP[s] = (float)tp;
    cntT[s] = (float)tt;
    __syncthreads();

    if (s < 2 * BINS) {
        const int b = s & 63;
        const float* cnt = (s < BINS) ? cntP : cntT;
        float h = 0.0f;
        #pragma unroll
        for (int u = -16; u <= 19; ++u) {
            int idx = 4 * b + u;
            if (idx >= 0 && idx < SBINS) {
                float t = (u - 1.5f) * 0.25f;
                h += __expf(-0.5f * t * t) * cnt[idx];
            }
        }
        if (s < BINS) histP[b] = h; else histT[b] = h;
    }
    __syncthreads();

    if (s < 64) {                       // wave 0: dual CDF + |diff| sum
        float cp = histP[s], ct = histT[s];
        #pragma unroll
        for (int off = 1; off < 64; off <<= 1) {
            float a = __shfl_up(cp, off, 64);
            float b = __shfl_up(ct, off, 64);
            if (s >= off) { cp += a; ct += b; }
        }
        float sp = __shfl(cp, 63, 64);
        float st = __shfl(ct, 63, 64);
        float diff = fabsf(cp / (sp + 1e-8f) - ct / (st + 1e-8f));
        #pragma unroll
        for (int off = 32; off; off >>= 1)
            diff += __shfl_xor(diff, off, 64);
        if (s == 0) {
            partial[ci] = diff;
            __threadfence();                       // release partial[ci]
            uint32_t old = atomicAdd(ticket, 1u);  // device-scope
            if (old == NCH - 1) {                  // last pair-block finishes
                __threadfence();                   // acquire others' partials
                float acc = 0.0f;
                #pragma unroll
                for (int i = 0; i < NCH; ++i) acc += partial[i];
                out[0] = acc / (float)(NCH * BINS);
            }
        }
    }
}

extern "C" void kernel_launch(void* const* d_in, const int* in_sizes, int n_in,
                              void* d_out, int out_size, void* d_ws, size_t ws_size,
                              hipStream_t stream)
{
    const float* pred   = (const float*)d_in[0];
    const float* target = (const float*)d_in[1];
    uint32_t* part    = (uint32_t*)d_ws;                         // 786 KB
    float*    partial = (float*)(part + (size_t)NIMG * CHUNKS * SBINS); // 12 f32
    uint32_t* ticket  = (uint32_t*)(partial + NCH);              // 1 u32

    hist_kernel<<<dim3(CHUNKS, NCH, 2), THREADS, 0, stream>>>(pred, target, part, ticket);
    conv_fin_kernel<<<NCH, SBINS, 0, stream>>>(part, partial, ticket, (float*)d_out);
}